// Round 2
// baseline (687.337 us; speedup 1.0000x reference)
//
#include <hip/hip_runtime.h>
#include <cstdint>
#include <cmath>

#define DIM    256
#define NSEQ   4096
#define NB     4
#define SCALE  0.17677669529663687f   // (DIM/NUM_HEADS)^-0.5 = 32^-0.5
#define THRESH 0.6f

#define TILE 128
#define LSTR 36   // LDS row stride in floats (pad: 128-row tiles, bank-clean for r=ty+16i)

// ---------------------------------------------------------------------------
// Weight transpose: Wt[c][k] = W[k][c], 4 matrices packed into one buffer.
// ---------------------------------------------------------------------------
__global__ void transpose4(const float* __restrict__ W0, const float* __restrict__ W1,
                           const float* __restrict__ W2, const float* __restrict__ W3,
                           float* __restrict__ Wt)
{
    int m = blockIdx.y;                 // 0..3
    int c = blockIdx.x;                 // 0..255 (output row = input col)
    int kk = threadIdx.x;               // 0..255
    const float* W = (m == 0) ? W0 : (m == 1) ? W1 : (m == 2) ? W2 : W3;
    Wt[(size_t)m * 65536 + (size_t)c * DIM + kk] = W[(size_t)kk * DIM + c];
}

// ---------------------------------------------------------------------------
// Staging: 128 rows x 32 k-cols of a row-major [*, 256] matrix into LDS.
// Thread t loads float4 at (row = p*32 + t/8, col = kc*32 + (t%8)*4).
// ---------------------------------------------------------------------------
__device__ __forceinline__ void stage_tile(const float* __restrict__ src,
                                           float* __restrict__ dst, int tid, int kc)
{
    int lr = tid >> 3;            // 0..31
    int lc = (tid & 7) << 2;      // 0,4,...,28
#pragma unroll
    for (int p = 0; p < 4; ++p) {
        int r = p * 32 + lr;
        const float4 val = *(const float4*)(src + (size_t)r * DIM + kc * 32 + lc);
        *(float4*)(dst + r * LSTR + lc) = val;
    }
}

// Staging with row gather + scale: A row r is scale[rb+r] * v[idx[rb+r]][...]
// idx is a GLOBAL v-row index (batch offset already folded in by flash_kernel).
__device__ __forceinline__ void stage_tile_gather(const float* __restrict__ vsrc,
                                                  const float* __restrict__ scl,
                                                  const int* __restrict__ sidx,
                                                  int rbase,
                                                  float* __restrict__ dst, int tid, int kc)
{
    int lr = tid >> 3;
    int lc = (tid & 7) << 2;
#pragma unroll
    for (int p = 0; p < 4; ++p) {
        int r = p * 32 + lr;
        int rg = rbase + r;
        float sc = scl[rg];
        int ix = sidx[rg];
        float4 val = *(const float4*)(vsrc + (size_t)ix * DIM + kc * 32 + lc);
        val.x *= sc; val.y *= sc; val.z *= sc; val.w *= sc;
        *(float4*)(dst + r * LSTR + lc) = val;
    }
}

// ---------------------------------------------------------------------------
// Inner product over one 32-wide K chunk: acc[i][j] += A[ty+16i][k]*B[tx+16j][k]
// ---------------------------------------------------------------------------
__device__ __forceinline__ void mm_inner(const float* __restrict__ lA,
                                         const float* __restrict__ lB,
                                         int ty, int tx, float acc[8][8])
{
#pragma unroll
    for (int k4 = 0; k4 < 8; ++k4) {
        float4 a[8], b[8];
#pragma unroll
        for (int i = 0; i < 8; ++i) a[i] = *(const float4*)(lA + (ty + 16 * i) * LSTR + 4 * k4);
#pragma unroll
        for (int j = 0; j < 8; ++j) b[j] = *(const float4*)(lB + (tx + 16 * j) * LSTR + 4 * k4);
#pragma unroll
        for (int i = 0; i < 8; ++i)
#pragma unroll
            for (int j = 0; j < 8; ++j) {
                acc[i][j] = fmaf(a[i].x, b[j].x, acc[i][j]);
                acc[i][j] = fmaf(a[i].y, b[j].y, acc[i][j]);
                acc[i][j] = fmaf(a[i].z, b[j].z, acc[i][j]);
                acc[i][j] = fmaf(a[i].w, b[j].w, acc[i][j]);
            }
    }
}

// ---------------------------------------------------------------------------
// Stage 1: q = x@Wq, k = y@Wk, v = x@Wv   (blockIdx.z selects which)
// ---------------------------------------------------------------------------
__global__ __launch_bounds__(256, 2)
void proj3_kernel(const float* __restrict__ x, const float* __restrict__ y,
                  const float* __restrict__ Wt,
                  float* __restrict__ q, float* __restrict__ k, float* __restrict__ v)
{
    __shared__ float lA[TILE * LSTR];
    __shared__ float lB[TILE * LSTR];
    int tid = threadIdx.x;
    int rb = blockIdx.x * TILE;
    int cb = blockIdx.y * TILE;
    int m = blockIdx.z;
    const float* A = (m == 1) ? y : x;
    const float* B = Wt + (size_t)m * 65536;
    float* C = (m == 0) ? q : (m == 1) ? k : v;

    float acc[8][8];
#pragma unroll
    for (int i = 0; i < 8; ++i)
#pragma unroll
        for (int j = 0; j < 8; ++j) acc[i][j] = 0.f;

    for (int kc = 0; kc < 8; ++kc) {
        __syncthreads();
        stage_tile(A + (size_t)rb * DIM, lA, tid, kc);
        stage_tile(B + (size_t)cb * DIM, lB, tid, kc);
        __syncthreads();
        mm_inner(lA, lB, tid >> 4, tid & 15, acc);
    }
    int ty = tid >> 4, tx = tid & 15;
#pragma unroll
    for (int i = 0; i < 8; ++i)
#pragma unroll
        for (int j = 0; j < 8; ++j)
            C[(size_t)(rb + ty + 16 * i) * DIM + cb + tx + 16 * j] = acc[i][j];
}

// ---------------------------------------------------------------------------
// Stage 2: fused score pass. Per block: 128 q-rows vs 1024 k-rows (m-split),
// online (max, sumexp, argmax) per row; no S materialization.
// argmax is stored as a GLOBAL v-row index (b*NSEQ + key).
// ---------------------------------------------------------------------------
__global__ __launch_bounds__(256, 2)
void flash_kernel(const float* __restrict__ q, const float* __restrict__ k,
                  float* __restrict__ pm, float* __restrict__ pl, int* __restrict__ pam)
{
    __shared__ float lA[TILE * LSTR];
    __shared__ float lB[TILE * LSTR];
    int tid = threadIdx.x;
    int ty = tid >> 4, tx = tid & 15;
    int qt = blockIdx.x;   // 0..31
    int ms = blockIdx.y;   // 0..3
    int b  = blockIdx.z;   // 0..3
    const float* Q = q + ((size_t)b * NSEQ + qt * TILE) * DIM;

    float rm[8], rl[8]; int ram[8];
#pragma unroll
    for (int i = 0; i < 8; ++i) { rm[i] = -INFINITY; rl[i] = 0.f; ram[i] = 0; }

    for (int mt = 0; mt < 8; ++mt) {
        const float* K = k + ((size_t)b * NSEQ + ms * 1024 + mt * TILE) * DIM;
        float acc[8][8];
#pragma unroll
        for (int i = 0; i < 8; ++i)
#pragma unroll
            for (int j = 0; j < 8; ++j) acc[i][j] = 0.f;

        for (int kc = 0; kc < 8; ++kc) {
            __syncthreads();
            stage_tile(Q, lA, tid, kc);
            stage_tile(K, lB, tid, kc);
            __syncthreads();
            mm_inner(lA, lB, ty, tx, acc);
        }

        // BUGFIX (R1): include batch offset so the argmax indexes v's global
        // [B*N, D] layout — previously batches 1..3 gathered batch 0's v.
        int cbase = b * NSEQ + ms * 1024 + mt * TILE + tx;
#pragma unroll
        for (int i = 0; i < 8; ++i) {
            // fold own 8 columns
            float m0 = acc[i][0] * SCALE; int j0 = 0;
#pragma unroll
            for (int j = 1; j < 8; ++j) {
                float s = acc[i][j] * SCALE;
                if (s > m0) { m0 = s; j0 = j; }
            }
            float l0 = 0.f;
#pragma unroll
            for (int j = 0; j < 8; ++j) l0 += __expf(acc[i][j] * SCALE - m0);
            int am0 = cbase + 16 * j0;
            // butterfly across the 16 tx lanes owning this row (symmetric merge
            // -> all 16 lanes converge to identical state)
#pragma unroll
            for (int d = 1; d < 16; d <<= 1) {
                float m2 = __shfl_xor(m0, d, 16);
                float l2 = __shfl_xor(l0, d, 16);
                int  am2 = __shfl_xor(am0, d, 16);
                if (m2 > m0) { l0 = l0 * __expf(m0 - m2) + l2; m0 = m2; am0 = am2; }
                else         { l0 = l0 + l2 * __expf(m2 - m0); }
            }
            // merge tile state into running state (replicated across tx lanes)
            if (m0 > rm[i]) { rl[i] = rl[i] * __expf(rm[i] - m0) + l0; rm[i] = m0; ram[i] = am0; }
            else            { rl[i] = rl[i] + l0 * __expf(m0 - rm[i]); }
        }
    }

    if (tx == 0) {
#pragma unroll
        for (int i = 0; i < 8; ++i) {
            int row = b * NSEQ + qt * TILE + ty + 16 * i;
            int idx = row * 4 + ms;
            pm[idx] = rm[i];
            pl[idx] = rl[i];
            pam[idx] = ram[i];
        }
    }
}

// ---------------------------------------------------------------------------
// Stage 2b: merge 4 m-split partials per row -> (scale, idx).
// p_max = 1/l; keep iff p_max >= THRESH (at most one prob can be >= 0.6).
// ---------------------------------------------------------------------------
__global__ void merge_kernel(const float* __restrict__ pm, const float* __restrict__ pl,
                             const int* __restrict__ pam,
                             float* __restrict__ scl, int* __restrict__ sidx)
{
    int row = blockIdx.x * 256 + threadIdx.x;
    float m = -INFINITY, l = 0.f; int am = 0;
#pragma unroll
    for (int s = 0; s < 4; ++s) {
        float m2 = pm[row * 4 + s];
        float l2 = pl[row * 4 + s];
        int  am2 = pam[row * 4 + s];
        if (m2 > m) { l = l * __expf(m - m2) + l2; m = m2; am = am2; }
        else        { l = l + l2 * __expf(m2 - m); }
    }
    float p = 1.f / l;
    scl[row] = (p >= THRESH) ? p : 0.f;
    sidx[row] = am;
}

// ---------------------------------------------------------------------------
// Stage 3: out[r] = (scale[r] * v[idx[r]]) @ Wp + bp  (gather fused in staging)
// ---------------------------------------------------------------------------
__global__ __launch_bounds__(256, 2)
void out_kernel(const float* __restrict__ v, const float* __restrict__ Wtp,
                const float* __restrict__ scl, const int* __restrict__ sidx,
                const float* __restrict__ bp, float* __restrict__ out)
{
    __shared__ float lA[TILE * LSTR];
    __shared__ float lB[TILE * LSTR];
    int tid = threadIdx.x;
    int rb = blockIdx.x * TILE;
    int cb = blockIdx.y * TILE;

    float acc[8][8];
#pragma unroll
    for (int i = 0; i < 8; ++i)
#pragma unroll
        for (int j = 0; j < 8; ++j) acc[i][j] = 0.f;

    for (int kc = 0; kc < 8; ++kc) {
        __syncthreads();
        stage_tile_gather(v, scl, sidx, rb, lA, tid, kc);
        stage_tile(Wtp + (size_t)cb * DIM, lB, tid, kc);
        __syncthreads();
        mm_inner(lA, lB, tid >> 4, tid & 15, acc);
    }
    int ty = tid >> 4, tx = tid & 15;
#pragma unroll
    for (int j = 0; j < 8; ++j) {
        float bias = bp[cb + tx + 16 * j];
#pragma unroll
        for (int i = 0; i < 8; ++i)
            out[(size_t)(rb + ty + 16 * i) * DIM + cb + tx + 16 * j] = acc[i][j] + bias;
    }
}

// ---------------------------------------------------------------------------
extern "C" void kernel_launch(void* const* d_in, const int* in_sizes, int n_in,
                              void* d_out, int out_size, void* d_ws, size_t ws_size,
                              hipStream_t stream)
{
    (void)in_sizes; (void)n_in; (void)out_size; (void)ws_size;
    const float* x  = (const float*)d_in[0];
    const float* y  = (const float*)d_in[1];
    const float* Wq = (const float*)d_in[2];
    const float* Wk = (const float*)d_in[3];
    const float* Wv = (const float*)d_in[4];
    const float* Wp = (const float*)d_in[5];
    const float* bp = (const float*)d_in[6];
    float* out = (float*)d_out;

    // workspace layout (floats): q,k,v (3 x 4194304), Wt (4 x 65536),
    // pm/pl/pam (3 x 65536), scl/sidx (2 x 16384)  => ~52.3 MB total
    float* ws  = (float*)d_ws;
    float* q   = ws;
    float* k   = q + 4194304;
    float* v   = k + 4194304;
    float* Wt  = v + 4194304;
    float* pm  = Wt + 4 * 65536;
    float* pl  = pm + 65536;
    int*  pam  = (int*)(pl + 65536);
    float* scl = (float*)(pam + 65536);
    int*  sidx = (int*)(scl + 16384);

    transpose4<<<dim3(256, 4), 256, 0, stream>>>(Wq, Wk, Wv, Wp, Wt);
    proj3_kernel<<<dim3(128, 2, 3), 256, 0, stream>>>(x, y, Wt, q, k, v);
    flash_kernel<<<dim3(32, 4, 4), 256, 0, stream>>>(q, k, pm, pl, pam);
    merge_kernel<<<64, 256, 0, stream>>>(pm, pl, pam, scl, sidx);
    out_kernel<<<dim3(128, 2), 256, 0, stream>>>(v, Wt + 3 * 65536, scl, sidx, bp, out);
}

// Round 3
// 413.808 us; speedup vs baseline: 1.6610x; 1.6610x over previous
//
#include <hip/hip_runtime.h>
#include <cstdint>
#include <cmath>

#define DIM    256
#define NSEQ   4096
#define SCALE  0.17677669529663687f   // 32^-0.5
#define THRESH 0.6f
#define BAND   2e-3f                  // recheck guard band around THRESH

#define TILE 128
#define LSTR 36   // fp32 LDS row stride (proj3 / out)

typedef __attribute__((ext_vector_type(8))) short bf16x8;
typedef __attribute__((ext_vector_type(4))) float f32x4;

__device__ __forceinline__ unsigned short bf16_rne(float v) {
    union { float f; unsigned u; } c; c.f = v;
    unsigned r = c.u + 0x7fffu + ((c.u >> 16) & 1u);
    return (unsigned short)(r >> 16);
}
__device__ __forceinline__ float bf16_to_f(unsigned short h) {
    union { unsigned u; float f; } c; c.u = ((unsigned)h) << 16;
    return c.f;
}

// ---------------------------------------------------------------------------
// Weight transpose: Wt[m][c][k] = W_m[k][c]
// ---------------------------------------------------------------------------
__global__ void transpose4(const float* __restrict__ W0, const float* __restrict__ W1,
                           const float* __restrict__ W2, const float* __restrict__ W3,
                           float* __restrict__ Wt)
{
    int m = blockIdx.y, c = blockIdx.x, kk = threadIdx.x;
    const float* W = (m == 0) ? W0 : (m == 1) ? W1 : (m == 2) ? W2 : W3;
    Wt[(size_t)m * 65536 + (size_t)c * DIM + kk] = W[(size_t)kk * DIM + c];
}

// ---------------------------------------------------------------------------
// fp32 tile helpers (proj3 / out)
// ---------------------------------------------------------------------------
__device__ __forceinline__ void stage_tile(const float* __restrict__ src,
                                           float* __restrict__ dst, int tid, int kc)
{
    int lr = tid >> 3, lc = (tid & 7) << 2;
#pragma unroll
    for (int p = 0; p < 4; ++p) {
        int r = p * 32 + lr;
        const float4 val = *(const float4*)(src + (size_t)r * DIM + kc * 32 + lc);
        *(float4*)(dst + r * LSTR + lc) = val;
    }
}

__device__ __forceinline__ void stage_tile_gather(const float* __restrict__ vsrc,
                                                  const float* __restrict__ scl,
                                                  const int* __restrict__ sidx,
                                                  int rbase,
                                                  float* __restrict__ dst, int tid, int kc)
{
    int lr = tid >> 3, lc = (tid & 7) << 2;
#pragma unroll
    for (int p = 0; p < 4; ++p) {
        int r = p * 32 + lr;
        int rg = rbase + r;
        float sc = scl[rg];
        int ix = sidx[rg];
        float4 val = *(const float4*)(vsrc + (size_t)ix * DIM + kc * 32 + lc);
        val.x *= sc; val.y *= sc; val.z *= sc; val.w *= sc;
        *(float4*)(dst + r * LSTR + lc) = val;
    }
}

__device__ __forceinline__ void mm_inner(const float* __restrict__ lA,
                                         const float* __restrict__ lB,
                                         int ty, int tx, float acc[8][8])
{
#pragma unroll
    for (int k4 = 0; k4 < 8; ++k4) {
        float4 a[8], b[8];
#pragma unroll
        for (int i = 0; i < 8; ++i) a[i] = *(const float4*)(lA + (ty + 16 * i) * LSTR + 4 * k4);
#pragma unroll
        for (int j = 0; j < 8; ++j) b[j] = *(const float4*)(lB + (tx + 16 * j) * LSTR + 4 * k4);
#pragma unroll
        for (int i = 0; i < 8; ++i)
#pragma unroll
            for (int j = 0; j < 8; ++j) {
                acc[i][j] = fmaf(a[i].x, b[j].x, acc[i][j]);
                acc[i][j] = fmaf(a[i].y, b[j].y, acc[i][j]);
                acc[i][j] = fmaf(a[i].z, b[j].z, acc[i][j]);
                acc[i][j] = fmaf(a[i].w, b[j].w, acc[i][j]);
            }
    }
}

// ---------------------------------------------------------------------------
// Stage 1: q = x@Wq (-> bf16 hi/lo only), k = y@Wk (-> fp32 + hi/lo),
//          v = x@Wv (-> fp32).  blockIdx.z selects m.
// ---------------------------------------------------------------------------
__global__ __launch_bounds__(256, 2)
void proj3_kernel(const float* __restrict__ x, const float* __restrict__ y,
                  const float* __restrict__ Wt,
                  float* __restrict__ kf, float* __restrict__ v,
                  unsigned short* __restrict__ qh, unsigned short* __restrict__ ql,
                  unsigned short* __restrict__ kh, unsigned short* __restrict__ kl)
{
    __shared__ float lA[TILE * LSTR];
    __shared__ float lB[TILE * LSTR];
    int tid = threadIdx.x;
    int rb = blockIdx.x * TILE;
    int cb = blockIdx.y * TILE;
    int m = blockIdx.z;
    const float* A = (m == 1) ? y : x;
    const float* B = Wt + (size_t)m * 65536;

    float acc[8][8];
#pragma unroll
    for (int i = 0; i < 8; ++i)
#pragma unroll
        for (int j = 0; j < 8; ++j) acc[i][j] = 0.f;

    for (int kc = 0; kc < 8; ++kc) {
        __syncthreads();
        stage_tile(A + (size_t)rb * DIM, lA, tid, kc);
        stage_tile(B + (size_t)cb * DIM, lB, tid, kc);
        __syncthreads();
        mm_inner(lA, lB, tid >> 4, tid & 15, acc);
    }
    int ty = tid >> 4, tx = tid & 15;
    if (m == 2) {
#pragma unroll
        for (int i = 0; i < 8; ++i)
#pragma unroll
            for (int j = 0; j < 8; ++j)
                v[(size_t)(rb + ty + 16 * i) * DIM + cb + tx + 16 * j] = acc[i][j];
    } else {
        unsigned short* H = (m == 0) ? qh : kh;
        unsigned short* L = (m == 0) ? ql : kl;
#pragma unroll
        for (int i = 0; i < 8; ++i)
#pragma unroll
            for (int j = 0; j < 8; ++j) {
                size_t rr = (size_t)(rb + ty + 16 * i) * DIM + cb + tx + 16 * j;
                float val = acc[i][j];
                if (m == 1) kf[rr] = val;
                unsigned short hb = bf16_rne(val);
                float hf = bf16_to_f(hb);
                unsigned short lb = bf16_rne(val - hf);
                H[rr] = hb; L[rr] = lb;
            }
    }
}

// ---------------------------------------------------------------------------
// Stage 2: MFMA flash score pass (bf16x3: qh*kh + qh*kl + ql*kh, fp32 acc).
// Block: 128 q-rows x 1024 keys (ms split).  16x16x32 bf16 MFMA.
// LDS fragment-major: per (rowblock, kstep), lane*16B linear -> conflict-free.
// Per-lane online (m,l,argmax); argmax is a GLOBAL v-row index.
// ---------------------------------------------------------------------------
__global__ __launch_bounds__(256, 2)
void flash_mfma(const unsigned short* __restrict__ qh, const unsigned short* __restrict__ ql,
                const unsigned short* __restrict__ kh, const unsigned short* __restrict__ kl,
                float* __restrict__ pm, float* __restrict__ pl, int* __restrict__ pam)
{
    __shared__ bf16x8 sQh[1024], sQl[1024], sKh[1024], sKl[1024]; // 16 KB each = 64 KB
    int tid = threadIdx.x;
    int lane = tid & 63;
    int w = tid >> 6;
    int qt = blockIdx.x, ms = blockIdx.y, b = blockIdx.z;

    size_t qrow0 = (size_t)b * NSEQ + (size_t)qt * 128;
    size_t krow0 = (size_t)b * NSEQ + (size_t)ms * 1024;

    int sr = tid >> 1;                                  // staged row 0..127
    int sh = tid & 1;                                   // kstep half of 64-chunk
    int ldsIdx = ((sr >> 4) * 2 + sh) * 64 + (sr & 15); // +16*p per piece

    float rm[2][4], rl[2][4]; int ram[2][4];
#pragma unroll
    for (int mi = 0; mi < 2; ++mi)
#pragma unroll
        for (int r = 0; r < 4; ++r) { rm[mi][r] = -INFINITY; rl[mi][r] = 0.f; ram[mi][r] = 0; }

    for (int mt = 0; mt < 8; ++mt) {
        f32x4 acc[2][8];
#pragma unroll
        for (int mi = 0; mi < 2; ++mi)
#pragma unroll
            for (int nt = 0; nt < 8; ++nt) acc[mi][nt] = (f32x4){0.f, 0.f, 0.f, 0.f};

        for (int kc = 0; kc < 4; ++kc) {
            __syncthreads();
            size_t qoff = (qrow0 + sr) * DIM + kc * 64 + sh * 32;
            size_t koff = (krow0 + mt * 128 + sr) * DIM + kc * 64 + sh * 32;
#pragma unroll
            for (int p = 0; p < 4; ++p) {
                sQh[ldsIdx + p * 16] = *(const bf16x8*)(qh + qoff + p * 8);
                sQl[ldsIdx + p * 16] = *(const bf16x8*)(ql + qoff + p * 8);
                sKh[ldsIdx + p * 16] = *(const bf16x8*)(kh + koff + p * 8);
                sKl[ldsIdx + p * 16] = *(const bf16x8*)(kl + koff + p * 8);
            }
            __syncthreads();
#pragma unroll
            for (int s = 0; s < 2; ++s) {
                bf16x8 a0h = sQh[((2 * w + 0) * 2 + s) * 64 + lane];
                bf16x8 a0l = sQl[((2 * w + 0) * 2 + s) * 64 + lane];
                bf16x8 a1h = sQh[((2 * w + 1) * 2 + s) * 64 + lane];
                bf16x8 a1l = sQl[((2 * w + 1) * 2 + s) * 64 + lane];
#pragma unroll
                for (int nt = 0; nt < 8; ++nt) {
                    bf16x8 bh = sKh[(nt * 2 + s) * 64 + lane];
                    bf16x8 bl = sKl[(nt * 2 + s) * 64 + lane];
                    acc[0][nt] = __builtin_amdgcn_mfma_f32_16x16x32_bf16(a0h, bh, acc[0][nt], 0, 0, 0);
                    acc[0][nt] = __builtin_amdgcn_mfma_f32_16x16x32_bf16(a0h, bl, acc[0][nt], 0, 0, 0);
                    acc[0][nt] = __builtin_amdgcn_mfma_f32_16x16x32_bf16(a0l, bh, acc[0][nt], 0, 0, 0);
                    acc[1][nt] = __builtin_amdgcn_mfma_f32_16x16x32_bf16(a1h, bh, acc[1][nt], 0, 0, 0);
                    acc[1][nt] = __builtin_amdgcn_mfma_f32_16x16x32_bf16(a1h, bl, acc[1][nt], 0, 0, 0);
                    acc[1][nt] = __builtin_amdgcn_mfma_f32_16x16x32_bf16(a1l, bh, acc[1][nt], 0, 0, 0);
                }
            }
        }
        // online-softmax epilogue for this 128-key tile
        int colbase = b * NSEQ + ms * 1024 + mt * 128 + (lane & 15);
#pragma unroll
        for (int mi = 0; mi < 2; ++mi)
#pragma unroll
            for (int r = 0; r < 4; ++r) {
                float mx = rm[mi][r]; int amx = ram[mi][r];
                float sv[8];
#pragma unroll
                for (int nt = 0; nt < 8; ++nt) {
                    sv[nt] = acc[mi][nt][r] * SCALE;
                    if (sv[nt] > mx) { mx = sv[nt]; amx = colbase + nt * 16; }
                }
                float sum = 0.f;
#pragma unroll
                for (int nt = 0; nt < 8; ++nt) sum += __expf(sv[nt] - mx);
                rl[mi][r] = rl[mi][r] * __expf(rm[mi][r] - mx) + sum;
                rm[mi][r] = mx; ram[mi][r] = amx;
            }
    }

    // fold across the 16 lanes sharing each row (xor 1,2,4,8 keeps quad = lane>>4)
#pragma unroll
    for (int mi = 0; mi < 2; ++mi)
#pragma unroll
        for (int r = 0; r < 4; ++r) {
            float m0 = rm[mi][r], l0 = rl[mi][r]; int am0 = ram[mi][r];
#pragma unroll
            for (int d = 1; d < 16; d <<= 1) {
                float m2 = __shfl_xor(m0, d);
                float l2 = __shfl_xor(l0, d);
                int  am2 = __shfl_xor(am0, d);
                if (m2 > m0) { l0 = l0 * __expf(m0 - m2) + l2; m0 = m2; am0 = am2; }
                else         { l0 = l0 + l2 * __expf(m2 - m0); }
            }
            if ((lane & 15) == 0) {
                int row = b * NSEQ + qt * 128 + (2 * w + mi) * 16 + (lane >> 4) * 4 + r;
                pm[row * 4 + ms] = m0; pl[row * 4 + ms] = l0; pam[row * 4 + ms] = am0;
            }
        }
}

// ---------------------------------------------------------------------------
// Stage 2b: merge 4 m-split partials -> (scale, idx); flag near-boundary rows.
// ---------------------------------------------------------------------------
__global__ void merge_kernel(const float* __restrict__ pm, const float* __restrict__ pl,
                             const int* __restrict__ pam,
                             float* __restrict__ scl, int* __restrict__ sidx,
                             int* __restrict__ susp)
{
    int row = blockIdx.x * 256 + threadIdx.x;
    float m = -INFINITY, l = 0.f; int am = 0;
#pragma unroll
    for (int s = 0; s < 4; ++s) {
        float m2 = pm[row * 4 + s];
        float l2 = pl[row * 4 + s];
        int  am2 = pam[row * 4 + s];
        if (m2 > m) { l = l * __expf(m - m2) + l2; m = m2; am = am2; }
        else        { l = l + l2 * __expf(m2 - m); }
    }
    float p = 1.f / l;
    scl[row] = (p >= THRESH) ? p : 0.f;
    sidx[row] = am;
    if (fabsf(p - THRESH) < BAND) {
        int i = atomicAdd(susp, 1);
        if (i < 4000) susp[2 + i] = row;
    }
}

// ---------------------------------------------------------------------------
// Stage 2c: exact fp32 recheck of near-boundary rows.
// q-row recomputed from x@Wq; full 4096-key softmax in fp32.
// ---------------------------------------------------------------------------
__global__ __launch_bounds__(256)
void recheck_kernel(const float* __restrict__ x, const float* __restrict__ Wtq,
                    const float* __restrict__ kf, const int* __restrict__ susp,
                    float* __restrict__ scl, int* __restrict__ sidx)
{
    __shared__ float qrow[DIM];
    __shared__ float rmw[4], rlw[4]; __shared__ int raw_[4];
    int tid = threadIdx.x;
    int count = susp[0]; if (count > 4000) count = 4000;

    for (int i = blockIdx.x; i < count; i += gridDim.x) {
        int row = susp[2 + i];
        int bb = row >> 12;                 // row / NSEQ
        __syncthreads();                    // protect qrow/rmw from prior iter
        {
            const float* xr = x + (size_t)row * DIM;
            const float* wr = Wtq + (size_t)tid * DIM;
            float a = 0.f;
            for (int d = 0; d < DIM; d += 4) {
                float4 xv = *(const float4*)(xr + d);
                float4 wv = *(const float4*)(wr + d);
                a = fmaf(xv.x, wv.x, a); a = fmaf(xv.y, wv.y, a);
                a = fmaf(xv.z, wv.z, a); a = fmaf(xv.w, wv.w, a);
            }
            qrow[tid] = a;
        }
        __syncthreads();

        int c = tid & 7;      // lane in 8-lane group (one key row per group)
        int g = tid >> 3;     // group 0..31
        float m = -INFINITY, l = 0.f; int am = 0;
        for (int n0 = 0; n0 < NSEQ; n0 += 32) {
            int n = n0 + g;
            const float* kr = kf + ((size_t)bb * NSEQ + n) * DIM;
            float dot = 0.f;
#pragma unroll
            for (int j = 0; j < 8; ++j) {
                int d = (j * 8 + c) * 4;
                float4 kv = *(const float4*)(kr + d);
                dot = fmaf(qrow[d], kv.x, dot);     dot = fmaf(qrow[d + 1], kv.y, dot);
                dot = fmaf(qrow[d + 2], kv.z, dot); dot = fmaf(qrow[d + 3], kv.w, dot);
            }
#pragma unroll
            for (int dd = 1; dd < 8; dd <<= 1) dot += __shfl_xor(dot, dd);
            float s = dot * SCALE;
            if (s > m) { l = l * __expf(m - s) + 1.f; m = s; am = bb * NSEQ + n; }
            else       { l += __expf(s - m); }
        }
#pragma unroll
        for (int dd = 8; dd < 64; dd <<= 1) {
            float m2 = __shfl_xor(m, dd); float l2 = __shfl_xor(l, dd); int a2 = __shfl_xor(am, dd);
            if (m2 > m) { l = l * __expf(m - m2) + l2; m = m2; am = a2; }
            else        { l += l2 * __expf(m2 - m); }
        }
        if ((tid & 63) == 0) { rmw[tid >> 6] = m; rlw[tid >> 6] = l; raw_[tid >> 6] = am; }
        __syncthreads();
        if (tid == 0) {
            float M = rmw[0], L = rlw[0]; int A = raw_[0];
            for (int wv = 1; wv < 4; ++wv) {
                float m2 = rmw[wv], l2 = rlw[wv]; int a2 = raw_[wv];
                if (m2 > M) { L = L * __expf(M - m2) + l2; M = m2; A = a2; }
                else        { L += l2 * __expf(m2 - M); }
            }
            float p = 1.f / L;
            scl[row] = (p >= THRESH) ? p : 0.f;
            sidx[row] = A;
        }
    }
}

// ---------------------------------------------------------------------------
// Stage 3: out[r] = (scale[r] * v[idx[r]]) @ Wp + bp
// ---------------------------------------------------------------------------
__global__ __launch_bounds__(256, 2)
void out_kernel(const float* __restrict__ v, const float* __restrict__ Wtp,
                const float* __restrict__ scl, const int* __restrict__ sidx,
                const float* __restrict__ bp, float* __restrict__ out)
{
    __shared__ float lA[TILE * LSTR];
    __shared__ float lB[TILE * LSTR];
    int tid = threadIdx.x;
    int rb = blockIdx.x * TILE;
    int cb = blockIdx.y * TILE;

    float acc[8][8];
#pragma unroll
    for (int i = 0; i < 8; ++i)
#pragma unroll
        for (int j = 0; j < 8; ++j) acc[i][j] = 0.f;

    for (int kc = 0; kc < 8; ++kc) {
        __syncthreads();
        stage_tile_gather(v, scl, sidx, rb, lA, tid, kc);
        stage_tile(Wtp + (size_t)cb * DIM, lB, tid, kc);
        __syncthreads();
        mm_inner(lA, lB, tid >> 4, tid & 15, acc);
    }
    int ty = tid >> 4, tx = tid & 15;
#pragma unroll
    for (int j = 0; j < 8; ++j) {
        float bias = bp[cb + tx + 16 * j];
#pragma unroll
        for (int i = 0; i < 8; ++i)
            out[(size_t)(rb + ty + 16 * i) * DIM + cb + tx + 16 * j] = acc[i][j] + bias;
    }
}

// ---------------------------------------------------------------------------
extern "C" void kernel_launch(void* const* d_in, const int* in_sizes, int n_in,
                              void* d_out, int out_size, void* d_ws, size_t ws_size,
                              hipStream_t stream)
{
    (void)in_sizes; (void)n_in; (void)out_size; (void)ws_size;
    const float* x  = (const float*)d_in[0];
    const float* y  = (const float*)d_in[1];
    const float* Wq = (const float*)d_in[2];
    const float* Wk = (const float*)d_in[3];
    const float* Wv = (const float*)d_in[4];
    const float* Wp = (const float*)d_in[5];
    const float* bp = (const float*)d_in[6];
    float* out = (float*)d_out;

    // ws layout (~69 MB): kf,v fp32; Wt; qh/ql/kh/kl bf16; partials; suspects
    float* ws = (float*)d_ws;
    float* kf = ws;
    float* v  = kf + 4194304;
    float* Wt = v + 4194304;
    unsigned short* qh = (unsigned short*)(Wt + 4 * 65536);
    unsigned short* ql = qh + 4194304;
    unsigned short* kh = ql + 4194304;
    unsigned short* kl = kh + 4194304;
    float* pm  = (float*)(kl + 4194304);
    float* pl  = pm + 65536;
    int*  pam  = (int*)(pl + 65536);
    float* scl = (float*)(pam + 65536);
    int*  sidx = (int*)(scl + 16384);
    int*  susp = sidx + 16384;

    transpose4<<<dim3(256, 4), 256, 0, stream>>>(Wq, Wk, Wv, Wp, Wt);
    proj3_kernel<<<dim3(128, 2, 3), 256, 0, stream>>>(x, y, Wt, kf, v, qh, ql, kh, kl);
    flash_mfma<<<dim3(32, 4, 4), 256, 0, stream>>>(qh, ql, kh, kl, pm, pl, pam);
    hipMemsetAsync(susp, 0, 4, stream);
    merge_kernel<<<64, 256, 0, stream>>>(pm, pl, pam, scl, sidx, susp);
    recheck_kernel<<<64, 256, 0, stream>>>(x, Wt, kf, susp, scl, sidx);
    out_kernel<<<dim3(128, 2), 256, 0, stream>>>(v, Wt + 3 * 65536, scl, sidx, bp, out);
}

// Round 4
// 316.519 us; speedup vs baseline: 2.1715x; 1.3074x over previous
//
#include <hip/hip_runtime.h>
#include <cstdint>
#include <cmath>

#define DIM     256
#define NSEQ    4096
#define SCALE   0.17677669529663687f   // 32^-0.5
#define THRESH  0.6f
#define BAND    0.01f                  // recheck guard band (≈14σ of fp16 score noise)
#define MAXSUSP 8000

using half8 = __attribute__((ext_vector_type(8))) _Float16;
using f32x4 = __attribute__((ext_vector_type(4))) float;

// ---------------------------------------------------------------------------
// Prep: transpose W's (fp32 for recheck, fp16 for MFMA B-operands); zero susp.
// ---------------------------------------------------------------------------
__global__ void prep_kernel(const float* __restrict__ W0, const float* __restrict__ W1,
                            const float* __restrict__ W2, const float* __restrict__ W3,
                            float* __restrict__ Wt, _Float16* __restrict__ Wth,
                            int* __restrict__ susp)
{
    int c = blockIdx.x, kk = threadIdx.x;
    if (c == 0 && kk == 0) { susp[0] = 0; susp[1] = 0; }
    const float* Ws[4] = {W0, W1, W2, W3};
#pragma unroll
    for (int m = 0; m < 4; ++m) {
        float val = Ws[m][(size_t)kk * DIM + c];
        size_t o = (size_t)m * 65536 + (size_t)c * DIM + kk;
        Wt[o] = val;
        Wth[o] = (_Float16)val;
    }
}

// ---------------------------------------------------------------------------
// Stage 1: q=x@Wq, k=y@Wk, v=x@Wv via fp16 MFMA (fp32 acc).
// Outputs: m=0 -> qh fp16; m=1 -> kh fp16 + kf fp32 (recheck); m=2 -> vh fp16.
// Block 128x128, 4 waves x (2 mi x 8 nt), K staged in 64-chunks.
// LDS frag-major layout: group G=(rowfrag*2+kstep), unit=((c&3)<<4)|(row&15).
// Store phases hit each bank exactly 2x (free); frag reads lane-linear (free).
// ---------------------------------------------------------------------------
__global__ __launch_bounds__(256, 2)
void proj3_mfma(const float* __restrict__ x, const float* __restrict__ y,
                const _Float16* __restrict__ Wth,
                _Float16* __restrict__ qh, _Float16* __restrict__ kh,
                float* __restrict__ kf, _Float16* __restrict__ vh)
{
    __shared__ half8 sA[1024];   // 128 x 64 fp16 = 16 KB
    __shared__ half8 sB[1024];
    int tid = threadIdx.x, w = tid >> 6, ln = tid & 63;
    int rb = blockIdx.x * 128, cb = blockIdx.y * 128, m = blockIdx.z;
    const float* A = (m == 1) ? y : x;
    const _Float16* B = Wth + (size_t)m * 65536;

    f32x4 acc[2][8];
#pragma unroll
    for (int mi = 0; mi < 2; ++mi)
#pragma unroll
        for (int nt = 0; nt < 8; ++nt) acc[mi][nt] = (f32x4){0.f, 0.f, 0.f, 0.f};

    int r = tid >> 1;
    int chalf = (tid & 1) * 4;
    for (int kc = 0; kc < 4; ++kc) {
        __syncthreads();
        const float*    asrc = A + (size_t)(rb + r) * DIM + kc * 64 + chalf * 8;
        const _Float16* bsrc = B + (size_t)(cb + r) * DIM + kc * 64 + chalf * 8;
#pragma unroll
        for (int cc = 0; cc < 4; ++cc) {
            int c = chalf + cc;
            float4 f0 = *(const float4*)(asrc + cc * 8);
            float4 f1 = *(const float4*)(asrc + cc * 8 + 4);
            half8 hv;
            hv[0] = (_Float16)f0.x; hv[1] = (_Float16)f0.y; hv[2] = (_Float16)f0.z; hv[3] = (_Float16)f0.w;
            hv[4] = (_Float16)f1.x; hv[5] = (_Float16)f1.y; hv[6] = (_Float16)f1.z; hv[7] = (_Float16)f1.w;
            int li = ((r >> 4) * 2 + (c >> 2)) * 64 + ((c & 3) << 4) + (r & 15);
            sA[li] = hv;
            sB[li] = *(const half8*)(bsrc + cc * 8);
        }
        __syncthreads();
#pragma unroll
        for (int s = 0; s < 2; ++s) {
            half8 a0 = sA[((w * 2 + 0) * 2 + s) * 64 + ln];
            half8 a1 = sA[((w * 2 + 1) * 2 + s) * 64 + ln];
#pragma unroll
            for (int nt = 0; nt < 8; ++nt) {
                half8 bv = sB[(nt * 2 + s) * 64 + ln];
                acc[0][nt] = __builtin_amdgcn_mfma_f32_16x16x32_f16(a0, bv, acc[0][nt], 0, 0, 0);
                acc[1][nt] = __builtin_amdgcn_mfma_f32_16x16x32_f16(a1, bv, acc[1][nt], 0, 0, 0);
            }
        }
    }
    int quad = ln >> 4, cix = ln & 15;
#pragma unroll
    for (int mi = 0; mi < 2; ++mi)
#pragma unroll
        for (int nt = 0; nt < 8; ++nt)
#pragma unroll
            for (int rr = 0; rr < 4; ++rr) {
                int row = rb + (w * 2 + mi) * 16 + quad * 4 + rr;
                int col = cb + nt * 16 + cix;
                size_t off = (size_t)row * DIM + col;
                float vv = acc[mi][nt][rr];
                if (m == 0)      qh[off] = (_Float16)vv;
                else if (m == 1) { kh[off] = (_Float16)vv; kf[off] = vv; }
                else             vh[off] = (_Float16)vv;
            }
}

// ---------------------------------------------------------------------------
// Stage 2: fp16 single-pass MFMA flash score pass.
// Block: 256 q-rows x 512 keys; 4 waves x (4 mi x 8 nt); mt=4 key tiles of 128.
// Per-lane online (m,l,argmax); argmax = GLOBAL v-row index.
// ---------------------------------------------------------------------------
__global__ __launch_bounds__(256, 2)
void flash_fp16(const _Float16* __restrict__ qh, const _Float16* __restrict__ kh,
                float* __restrict__ pm, float* __restrict__ pl, int* __restrict__ pam)
{
    __shared__ half8 sQ[2048];   // 256 x 64 fp16 = 32 KB
    __shared__ half8 sK[1024];   // 128 x 64 fp16 = 16 KB
    int tid = threadIdx.x, w = tid >> 6, ln = tid & 63;
    int qt = blockIdx.x, ms = blockIdx.y, b = blockIdx.z;
    size_t qrow0 = (size_t)b * NSEQ + (size_t)qt * 256;
    size_t krow0 = (size_t)b * NSEQ + (size_t)ms * 512;

    float rm[4][4], rl[4][4]; int ram[4][4];
#pragma unroll
    for (int mi = 0; mi < 4; ++mi)
#pragma unroll
        for (int rr = 0; rr < 4; ++rr) { rm[mi][rr] = -INFINITY; rl[mi][rr] = 0.f; ram[mi][rr] = 0; }

    int r2 = tid >> 1, chalf = (tid & 1) * 4;
    for (int mt = 0; mt < 4; ++mt) {
        f32x4 acc[4][8];
#pragma unroll
        for (int mi = 0; mi < 4; ++mi)
#pragma unroll
            for (int nt = 0; nt < 8; ++nt) acc[mi][nt] = (f32x4){0.f, 0.f, 0.f, 0.f};

        for (int kc = 0; kc < 4; ++kc) {
            __syncthreads();
            const _Float16* qsrc = qh + (qrow0 + tid) * DIM + kc * 64;
#pragma unroll
            for (int c = 0; c < 8; ++c)
                sQ[((tid >> 4) * 2 + (c >> 2)) * 64 + ((c & 3) << 4) + (tid & 15)] =
                    *(const half8*)(qsrc + c * 8);
            const _Float16* ksrc = kh + (krow0 + mt * 128 + r2) * DIM + kc * 64 + chalf * 8;
#pragma unroll
            for (int cc = 0; cc < 4; ++cc) {
                int c = chalf + cc;
                sK[((r2 >> 4) * 2 + (c >> 2)) * 64 + ((c & 3) << 4) + (r2 & 15)] =
                    *(const half8*)(ksrc + cc * 8);
            }
            __syncthreads();
#pragma unroll
            for (int s = 0; s < 2; ++s) {
                half8 aq[4];
#pragma unroll
                for (int mi = 0; mi < 4; ++mi) aq[mi] = sQ[((w * 4 + mi) * 2 + s) * 64 + ln];
#pragma unroll
                for (int nt = 0; nt < 8; ++nt) {
                    half8 bk = sK[(nt * 2 + s) * 64 + ln];
#pragma unroll
                    for (int mi = 0; mi < 4; ++mi)
                        acc[mi][nt] = __builtin_amdgcn_mfma_f32_16x16x32_f16(aq[mi], bk, acc[mi][nt], 0, 0, 0);
                }
            }
        }
        int keybase = b * NSEQ + ms * 512 + mt * 128 + (ln & 15);
#pragma unroll
        for (int mi = 0; mi < 4; ++mi)
#pragma unroll
            for (int rr = 0; rr < 4; ++rr) {
                float mx = rm[mi][rr]; int amx = ram[mi][rr];
                float sv[8];
#pragma unroll
                for (int nt = 0; nt < 8; ++nt) {
                    sv[nt] = acc[mi][nt][rr] * SCALE;
                    if (sv[nt] > mx) { mx = sv[nt]; amx = keybase + nt * 16; }
                }
                float sum = 0.f;
#pragma unroll
                for (int nt = 0; nt < 8; ++nt) sum += __expf(sv[nt] - mx);
                rl[mi][rr] = rl[mi][rr] * __expf(rm[mi][rr] - mx) + sum;
                rm[mi][rr] = mx; ram[mi][rr] = amx;
            }
    }

    // fold the 16 key-lanes per row (xor<16 keeps quad = ln>>4 fixed)
#pragma unroll
    for (int mi = 0; mi < 4; ++mi)
#pragma unroll
        for (int rr = 0; rr < 4; ++rr) {
            float m0 = rm[mi][rr], l0 = rl[mi][rr]; int am0 = ram[mi][rr];
#pragma unroll
            for (int d = 1; d < 16; d <<= 1) {
                float m2 = __shfl_xor(m0, d);
                float l2 = __shfl_xor(l0, d);
                int  am2 = __shfl_xor(am0, d);
                if (m2 > m0) { l0 = l0 * __expf(m0 - m2) + l2; m0 = m2; am0 = am2; }
                else         { l0 = l0 + l2 * __expf(m2 - m0); }
            }
            if ((ln & 15) == 0) {
                int row = b * NSEQ + qt * 256 + w * 64 + mi * 16 + (ln >> 4) * 4 + rr;
                pm[row * 8 + ms] = m0; pl[row * 8 + ms] = l0; pam[row * 8 + ms] = am0;
            }
        }
}

// ---------------------------------------------------------------------------
// Stage 2b: merge 8 ms-split partials -> (scale, idx); flag near-boundary rows.
// ---------------------------------------------------------------------------
__global__ void merge_kernel(const float* __restrict__ pm, const float* __restrict__ pl,
                             const int* __restrict__ pam,
                             float* __restrict__ scl, int* __restrict__ sidx,
                             int* __restrict__ susp)
{
    int row = blockIdx.x * 256 + threadIdx.x;
    float m = -INFINITY, l = 0.f; int am = 0;
#pragma unroll
    for (int s = 0; s < 8; ++s) {
        float m2 = pm[row * 8 + s];
        float l2 = pl[row * 8 + s];
        int  am2 = pam[row * 8 + s];
        if (m2 > m) { l = l * __expf(m - m2) + l2; m = m2; am = am2; }
        else        { l = l + l2 * __expf(m2 - m); }
    }
    float p = 1.f / l;
    scl[row] = (p >= THRESH) ? p : 0.f;
    sidx[row] = am;
    if (fabsf(p - THRESH) < BAND) {
        int i = atomicAdd(susp, 1);
        if (i < MAXSUSP) susp[2 + i] = row;
    }
}

// ---------------------------------------------------------------------------
// Stage 2c: exact fp32 recheck of near-boundary rows (q from x@Wq, fp32 k).
// ---------------------------------------------------------------------------
__global__ __launch_bounds__(256)
void recheck_kernel(const float* __restrict__ x, const float* __restrict__ Wtq,
                    const float* __restrict__ kf, const int* __restrict__ susp,
                    float* __restrict__ scl, int* __restrict__ sidx)
{
    __shared__ float qrow[DIM];
    __shared__ float rmw[4], rlw[4]; __shared__ int raw_[4];
    int tid = threadIdx.x;
    int count = susp[0]; if (count > MAXSUSP) count = MAXSUSP;

    for (int i = blockIdx.x; i < count; i += gridDim.x) {
        int row = susp[2 + i];
        int bb = row >> 12;
        __syncthreads();
        {
            const float* xr = x + (size_t)row * DIM;
            const float* wr = Wtq + (size_t)tid * DIM;
            float a = 0.f;
            for (int d = 0; d < DIM; d += 4) {
                float4 xv = *(const float4*)(xr + d);
                float4 wv = *(const float4*)(wr + d);
                a = fmaf(xv.x, wv.x, a); a = fmaf(xv.y, wv.y, a);
                a = fmaf(xv.z, wv.z, a); a = fmaf(xv.w, wv.w, a);
            }
            qrow[tid] = a;
        }
        __syncthreads();

        int c = tid & 7, g = tid >> 3;
        float m = -INFINITY, l = 0.f; int am = 0;
        for (int n0 = 0; n0 < NSEQ; n0 += 32) {
            int n = n0 + g;
            const float* kr = kf + ((size_t)bb * NSEQ + n) * DIM;
            float dot = 0.f;
#pragma unroll
            for (int j = 0; j < 8; ++j) {
                int d = (j * 8 + c) * 4;
                float4 kv = *(const float4*)(kr + d);
                dot = fmaf(qrow[d], kv.x, dot);     dot = fmaf(qrow[d + 1], kv.y, dot);
                dot = fmaf(qrow[d + 2], kv.z, dot); dot = fmaf(qrow[d + 3], kv.w, dot);
            }
#pragma unroll
            for (int dd = 1; dd < 8; dd <<= 1) dot += __shfl_xor(dot, dd);
            float s = dot * SCALE;
            if (s > m) { l = l * __expf(m - s) + 1.f; m = s; am = bb * NSEQ + n; }
            else       { l += __expf(s - m); }
        }
#pragma unroll
        for (int dd = 8; dd < 64; dd <<= 1) {
            float m2 = __shfl_xor(m, dd); float l2 = __shfl_xor(l, dd); int a2 = __shfl_xor(am, dd);
            if (m2 > m) { l = l * __expf(m - m2) + l2; m = m2; am = a2; }
            else        { l += l2 * __expf(m2 - m); }
        }
        if ((tid & 63) == 0) { rmw[tid >> 6] = m; rlw[tid >> 6] = l; raw_[tid >> 6] = am; }
        __syncthreads();
        if (tid == 0) {
            float M = rmw[0], L = rlw[0]; int A = raw_[0];
            for (int wv = 1; wv < 4; ++wv) {
                float m2 = rmw[wv], l2 = rlw[wv]; int a2 = raw_[wv];
                if (m2 > M) { L = L * __expf(M - m2) + l2; M = m2; A = a2; }
                else        { L += l2 * __expf(m2 - M); }
            }
            float p = 1.f / L;
            scl[row] = (p >= THRESH) ? p : 0.f;
            sidx[row] = A;
        }
    }
}

// ---------------------------------------------------------------------------
// Stage 3: out[r] = scl[r] * (vh[idx[r]] @ Wp) + bp  (fp16 MFMA, fp32 scale)
// ---------------------------------------------------------------------------
__global__ __launch_bounds__(256, 2)
void out_mfma(const _Float16* __restrict__ vh, const _Float16* __restrict__ Wph,
              const float* __restrict__ scl, const int* __restrict__ sidx,
              const float* __restrict__ bp, float* __restrict__ out)
{
    __shared__ half8 sA[1024];
    __shared__ half8 sB[1024];
    int tid = threadIdx.x, w = tid >> 6, ln = tid & 63;
    int rb = blockIdx.x * 128, cb = blockIdx.y * 128;

    f32x4 acc[2][8];
#pragma unroll
    for (int mi = 0; mi < 2; ++mi)
#pragma unroll
        for (int nt = 0; nt < 8; ++nt) acc[mi][nt] = (f32x4){0.f, 0.f, 0.f, 0.f};

    int r = tid >> 1, chalf = (tid & 1) * 4;
    int gix = sidx[rb + r];
    for (int kc = 0; kc < 4; ++kc) {
        __syncthreads();
        const _Float16* asrc = vh + (size_t)gix * DIM + kc * 64 + chalf * 8;
        const _Float16* bsrc = Wph + (size_t)(cb + r) * DIM + kc * 64 + chalf * 8;
#pragma unroll
        for (int cc = 0; cc < 4; ++cc) {
            int c = chalf + cc;
            int li = ((r >> 4) * 2 + (c >> 2)) * 64 + ((c & 3) << 4) + (r & 15);
            sA[li] = *(const half8*)(asrc + cc * 8);
            sB[li] = *(const half8*)(bsrc + cc * 8);
        }
        __syncthreads();
#pragma unroll
        for (int s = 0; s < 2; ++s) {
            half8 a0 = sA[((w * 2 + 0) * 2 + s) * 64 + ln];
            half8 a1 = sA[((w * 2 + 1) * 2 + s) * 64 + ln];
#pragma unroll
            for (int nt = 0; nt < 8; ++nt) {
                half8 bv = sB[(nt * 2 + s) * 64 + ln];
                acc[0][nt] = __builtin_amdgcn_mfma_f32_16x16x32_f16(a0, bv, acc[0][nt], 0, 0, 0);
                acc[1][nt] = __builtin_amdgcn_mfma_f32_16x16x32_f16(a1, bv, acc[1][nt], 0, 0, 0);
            }
        }
    }
    int quad = ln >> 4, cix = ln & 15;
#pragma unroll
    for (int mi = 0; mi < 2; ++mi)
#pragma unroll
        for (int rr = 0; rr < 4; ++rr) {
            int row = rb + (w * 2 + mi) * 16 + quad * 4 + rr;
            float sc = scl[row];
#pragma unroll
            for (int nt = 0; nt < 8; ++nt) {
                int col = cb + nt * 16 + cix;
                out[(size_t)row * DIM + col] = acc[mi][nt][rr] * sc + bp[col];
            }
        }
}

// ---------------------------------------------------------------------------
extern "C" void kernel_launch(void* const* d_in, const int* in_sizes, int n_in,
                              void* d_out, int out_size, void* d_ws, size_t ws_size,
                              hipStream_t stream)
{
    (void)in_sizes; (void)n_in; (void)out_size; (void)ws_size;
    const float* x  = (const float*)d_in[0];
    const float* y  = (const float*)d_in[1];
    const float* Wq = (const float*)d_in[2];
    const float* Wk = (const float*)d_in[3];
    const float* Wv = (const float*)d_in[4];
    const float* Wp = (const float*)d_in[5];
    const float* bp = (const float*)d_in[6];
    float* out = (float*)d_out;

    // ws layout (~45 MB)
    float* p0 = (float*)d_ws;
    float* kf = p0;                 p0 += 4194304;
    float* Wt = p0;                 p0 += 4 * 65536;
    _Float16* Wth = (_Float16*)p0;  p0 += 4 * 65536 / 2;
    _Float16* qh  = (_Float16*)p0;  p0 += 2097152;
    _Float16* kh  = (_Float16*)p0;  p0 += 2097152;
    _Float16* vh  = (_Float16*)p0;  p0 += 2097152;
    float* pm  = p0;                p0 += 131072;
    float* pl  = p0;                p0 += 131072;
    int*  pam  = (int*)p0;          p0 += 131072;
    float* scl = p0;                p0 += 16384;
    int*  sidx = (int*)p0;          p0 += 16384;
    int*  susp = (int*)p0;

    prep_kernel<<<256, 256, 0, stream>>>(Wq, Wk, Wv, Wp, Wt, Wth, susp);
    proj3_mfma<<<dim3(128, 2, 3), 256, 0, stream>>>(x, y, Wth, qh, kh, kf, vh);
    flash_fp16<<<dim3(16, 8, 4), 256, 0, stream>>>(qh, kh, pm, pl, pam);
    merge_kernel<<<64, 256, 0, stream>>>(pm, pl, pam, scl, sidx, susp);
    recheck_kernel<<<128, 256, 0, stream>>>(x, Wt, kf, susp, scl, sidx);
    out_mfma<<<dim3(128, 2), 256, 0, stream>>>(vh, Wth + 3 * 65536, scl, sidx, bp, out);
}

// Round 5
// 259.308 us; speedup vs baseline: 2.6507x; 1.2206x over previous
//
#include <hip/hip_runtime.h>
#include <cstdint>
#include <cmath>

#define DIM     256
#define NSEQ    4096
#define SCALE   0.17677669529663687f   // 32^-0.5
#define THRESH  0.6f
#define BAND    0.01f                  // recheck guard band
#define MAXSUSP 8000

using half8 = __attribute__((ext_vector_type(8))) _Float16;
using half4 = __attribute__((ext_vector_type(4))) _Float16;
using f32x4 = __attribute__((ext_vector_type(4))) float;

// ---------------------------------------------------------------------------
// Prep: coalesced LDS-tiled transpose. Wth[m][c][k] = W_m[k][c] (fp16);
// Wt[c][k] = Wq[k][c] (fp32, recheck only). Zeroes susp.
// ---------------------------------------------------------------------------
__global__ void prep_kernel(const float* __restrict__ W0, const float* __restrict__ W1,
                            const float* __restrict__ W2, const float* __restrict__ W3,
                            float* __restrict__ Wt, _Float16* __restrict__ Wth,
                            int* __restrict__ susp)
{
    __shared__ float tile[64][68];   // stride 68: float4-aligned, 4*68%32=16 -> conflict-free col reads
    int t = threadIdx.x;
    int m = blockIdx.x >> 4;
    int ti = blockIdx.x & 15;
    int tr = (ti >> 2) * 64, tc = (ti & 3) * 64;
    const float* W = (m == 0) ? W0 : (m == 1) ? W1 : (m == 2) ? W2 : W3;
    if (blockIdx.x == 0 && t < 2) susp[t] = 0;
    int rr = t >> 4, c4 = (t & 15) * 4;
#pragma unroll
    for (int p = 0; p < 4; ++p) {
        int row = p * 16 + rr;
        *(float4*)&tile[row][c4] = *(const float4*)(W + (size_t)(tr + row) * DIM + tc + c4);
    }
    __syncthreads();
#pragma unroll
    for (int p = 0; p < 4; ++p) {
        int c = p * 16 + rr;
        float4 v;
        v.x = tile[c4 + 0][c]; v.y = tile[c4 + 1][c];
        v.z = tile[c4 + 2][c]; v.w = tile[c4 + 3][c];
        size_t ot = (size_t)(tc + c) * DIM + tr + c4;
        if (m == 0) *(float4*)(Wt + ot) = v;
        half4 hv;
        hv[0] = (_Float16)v.x; hv[1] = (_Float16)v.y;
        hv[2] = (_Float16)v.z; hv[3] = (_Float16)v.w;
        *(half4*)(Wth + (size_t)m * 65536 + ot) = hv;
    }
}

// ---------------------------------------------------------------------------
// Stage 1: q=x@Wq, k=y@Wk, v=x@Wv via fp16 MFMA (fp32 acc).
// m=0 -> qh fp16; m=1 -> kh fp16 + kf fp32 (recheck); m=2 -> vh fp16.
// ---------------------------------------------------------------------------
__global__ __launch_bounds__(256, 2)
void proj3_mfma(const float* __restrict__ x, const float* __restrict__ y,
                const _Float16* __restrict__ Wth,
                _Float16* __restrict__ qh, _Float16* __restrict__ kh,
                float* __restrict__ kf, _Float16* __restrict__ vh)
{
    __shared__ half8 sA[1024];   // 128 x 64 fp16 = 16 KB
    __shared__ half8 sB[1024];
    int tid = threadIdx.x, w = tid >> 6, ln = tid & 63;
    int rb = blockIdx.x * 128, cb = blockIdx.y * 128, m = blockIdx.z;
    const float* A = (m == 1) ? y : x;
    const _Float16* B = Wth + (size_t)m * 65536;

    f32x4 acc[2][8];
#pragma unroll
    for (int mi = 0; mi < 2; ++mi)
#pragma unroll
        for (int nt = 0; nt < 8; ++nt) acc[mi][nt] = (f32x4){0.f, 0.f, 0.f, 0.f};

    int r = tid >> 1;
    int chalf = (tid & 1) * 4;
    for (int kc = 0; kc < 4; ++kc) {
        __syncthreads();
        const float*    asrc = A + (size_t)(rb + r) * DIM + kc * 64 + chalf * 8;
        const _Float16* bsrc = B + (size_t)(cb + r) * DIM + kc * 64 + chalf * 8;
#pragma unroll
        for (int cc = 0; cc < 4; ++cc) {
            int c = chalf + cc;
            float4 f0 = *(const float4*)(asrc + cc * 8);
            float4 f1 = *(const float4*)(asrc + cc * 8 + 4);
            half8 hv;
            hv[0] = (_Float16)f0.x; hv[1] = (_Float16)f0.y; hv[2] = (_Float16)f0.z; hv[3] = (_Float16)f0.w;
            hv[4] = (_Float16)f1.x; hv[5] = (_Float16)f1.y; hv[6] = (_Float16)f1.z; hv[7] = (_Float16)f1.w;
            int li = ((r >> 4) * 2 + (c >> 2)) * 64 + ((c & 3) << 4) + (r & 15);
            sA[li] = hv;
            sB[li] = *(const half8*)(bsrc + cc * 8);
        }
        __syncthreads();
#pragma unroll
        for (int s = 0; s < 2; ++s) {
            half8 a0 = sA[((w * 2 + 0) * 2 + s) * 64 + ln];
            half8 a1 = sA[((w * 2 + 1) * 2 + s) * 64 + ln];
#pragma unroll
            for (int nt = 0; nt < 8; ++nt) {
                half8 bv = sB[(nt * 2 + s) * 64 + ln];
                acc[0][nt] = __builtin_amdgcn_mfma_f32_16x16x32_f16(a0, bv, acc[0][nt], 0, 0, 0);
                acc[1][nt] = __builtin_amdgcn_mfma_f32_16x16x32_f16(a1, bv, acc[1][nt], 0, 0, 0);
            }
        }
    }
    int quad = ln >> 4, cix = ln & 15;
#pragma unroll
    for (int mi = 0; mi < 2; ++mi)
#pragma unroll
        for (int nt = 0; nt < 8; ++nt)
#pragma unroll
            for (int rr = 0; rr < 4; ++rr) {
                int row = rb + (w * 2 + mi) * 16 + quad * 4 + rr;
                int col = cb + nt * 16 + cix;
                size_t off = (size_t)row * DIM + col;
                float vv = acc[mi][nt][rr];
                if (m == 0)      qh[off] = (_Float16)vv;
                else if (m == 1) { kh[off] = (_Float16)vv; kf[off] = vv; }
                else             vh[off] = (_Float16)vv;
            }
}

// ---------------------------------------------------------------------------
// Stage 2: fp16 MFMA flash score pass, restructured:
//  - q fragments in REGISTERS (loaded once, MFMA A-layout: row=ln&15, k=(ln>>4)*8)
//  - grid (g = ms+4*b, qt): same-XCD blocks share one k-slice -> L2-resident k
//  - 8 k-tiles of 128 keys, single 64 KB LDS buffer, 2 blocks/CU
// Per-lane online (m,l,argmax); argmax = GLOBAL v-row index.
// ---------------------------------------------------------------------------
__global__ __launch_bounds__(256, 2)
void flash_fp16(const _Float16* __restrict__ qh, const _Float16* __restrict__ kh,
                float* __restrict__ pm, float* __restrict__ pl, int* __restrict__ pam)
{
    __shared__ half8 sK[4096];   // 128 keys x 256 dims fp16 = 64 KB
    int tid = threadIdx.x, w = tid >> 6, ln = tid & 63;
    int g = blockIdx.x;          // ms + 4*b  (fast dim -> XCD = g%8 shares k-slice)
    int qt = blockIdx.y;
    int ms = g & 3, b = g >> 2;
    size_t qbase = (size_t)b * NSEQ + qt * 128 + w * 32;
    size_t krow0 = (size_t)b * NSEQ + ms * 1024;

    // one-time q fragment load (A-layout verified by R4's LDS path)
    half8 qf[2][8];
#pragma unroll
    for (int mi = 0; mi < 2; ++mi) {
        const _Float16* qsrc = qh + (qbase + mi * 16 + (ln & 15)) * DIM + (ln >> 4) * 8;
#pragma unroll
        for (int ks = 0; ks < 8; ++ks)
            qf[mi][ks] = *(const half8*)(qsrc + ks * 32);
    }

    float rm[2][4], rl[2][4]; int ram[2][4];
#pragma unroll
    for (int mi = 0; mi < 2; ++mi)
#pragma unroll
        for (int rr = 0; rr < 4; ++rr) { rm[mi][rr] = -INFINITY; rl[mi][rr] = 0.f; ram[mi][rr] = 0; }

    int r = tid >> 1, h = tid & 1;
    int nt_ = r >> 4, m_ = r & 15;
    for (int kt = 0; kt < 8; ++kt) {
        __syncthreads();
        const _Float16* ksrc = kh + (krow0 + kt * 128 + r) * DIM + h * 128;
#pragma unroll
        for (int cc = 0; cc < 16; ++cc) {
            int c = h * 16 + cc;                      // dim chunk (8 halves)
            sK[(nt_ * 8 + (c >> 2)) * 64 + ((c & 3) << 4) + m_] = *(const half8*)(ksrc + cc * 8);
        }
        __syncthreads();

        f32x4 acc[2][8];
#pragma unroll
        for (int mi = 0; mi < 2; ++mi)
#pragma unroll
            for (int nt = 0; nt < 8; ++nt) acc[mi][nt] = (f32x4){0.f, 0.f, 0.f, 0.f};

#pragma unroll
        for (int nt = 0; nt < 8; ++nt)
#pragma unroll
            for (int ks = 0; ks < 8; ++ks) {
                half8 bk = sK[(nt * 8 + ks) * 64 + ln];
                acc[0][nt] = __builtin_amdgcn_mfma_f32_16x16x32_f16(qf[0][ks], bk, acc[0][nt], 0, 0, 0);
                acc[1][nt] = __builtin_amdgcn_mfma_f32_16x16x32_f16(qf[1][ks], bk, acc[1][nt], 0, 0, 0);
            }

        int keybase = b * NSEQ + ms * 1024 + kt * 128 + (ln & 15);
#pragma unroll
        for (int mi = 0; mi < 2; ++mi)
#pragma unroll
            for (int rr = 0; rr < 4; ++rr) {
                float mx = rm[mi][rr]; int amx = ram[mi][rr];
                float sv[8];
#pragma unroll
                for (int nt = 0; nt < 8; ++nt) {
                    sv[nt] = acc[mi][nt][rr] * SCALE;
                    if (sv[nt] > mx) { mx = sv[nt]; amx = keybase + nt * 16; }
                }
                float sum = 0.f;
#pragma unroll
                for (int nt = 0; nt < 8; ++nt) sum += __expf(sv[nt] - mx);
                rl[mi][rr] = rl[mi][rr] * __expf(rm[mi][rr] - mx) + sum;
                rm[mi][rr] = mx; ram[mi][rr] = amx;
            }
    }

    // fold the 16 key-lanes per row (xor<16 keeps quad = ln>>4 fixed)
#pragma unroll
    for (int mi = 0; mi < 2; ++mi)
#pragma unroll
        for (int rr = 0; rr < 4; ++rr) {
            float m0 = rm[mi][rr], l0 = rl[mi][rr]; int am0 = ram[mi][rr];
#pragma unroll
            for (int d = 1; d < 16; d <<= 1) {
                float m2 = __shfl_xor(m0, d);
                float l2 = __shfl_xor(l0, d);
                int  am2 = __shfl_xor(am0, d);
                if (m2 > m0) { l0 = l0 * __expf(m0 - m2) + l2; m0 = m2; am0 = am2; }
                else         { l0 = l0 + l2 * __expf(m2 - m0); }
            }
            if ((ln & 15) == 0) {
                int row = b * NSEQ + qt * 128 + w * 32 + mi * 16 + (ln >> 4) * 4 + rr;
                pm[row * 4 + ms] = m0; pl[row * 4 + ms] = l0; pam[row * 4 + ms] = am0;
            }
        }
}

// ---------------------------------------------------------------------------
// Stage 2b: merge 4 ms-split partials -> (scale, idx); flag near-boundary rows.
// ---------------------------------------------------------------------------
__global__ void merge_kernel(const float* __restrict__ pm, const float* __restrict__ pl,
                             const int* __restrict__ pam,
                             float* __restrict__ scl, int* __restrict__ sidx,
                             int* __restrict__ susp)
{
    int row = blockIdx.x * 256 + threadIdx.x;
    float m = -INFINITY, l = 0.f; int am = 0;
#pragma unroll
    for (int s = 0; s < 4; ++s) {
        float m2 = pm[row * 4 + s];
        float l2 = pl[row * 4 + s];
        int  am2 = pam[row * 4 + s];
        if (m2 > m) { l = l * __expf(m - m2) + l2; m = m2; am = am2; }
        else        { l = l + l2 * __expf(m2 - m); }
    }
    float p = 1.f / l;
    scl[row] = (p >= THRESH) ? p : 0.f;
    sidx[row] = am;
    if (fabsf(p - THRESH) < BAND) {
        int i = atomicAdd(susp, 1);
        if (i < MAXSUSP) susp[2 + i] = row;
    }
}

// ---------------------------------------------------------------------------
// Stage 2c: exact fp32 recheck of near-boundary rows (q from x@Wq, fp32 k).
// ---------------------------------------------------------------------------
__global__ __launch_bounds__(256)
void recheck_kernel(const float* __restrict__ x, const float* __restrict__ Wtq,
                    const float* __restrict__ kf, const int* __restrict__ susp,
                    float* __restrict__ scl, int* __restrict__ sidx)
{
    __shared__ float qrow[DIM];
    __shared__ float rmw[4], rlw[4]; __shared__ int raw_[4];
    int tid = threadIdx.x;
    int count = susp[0]; if (count > MAXSUSP) count = MAXSUSP;

    for (int i = blockIdx.x; i < count; i += gridDim.x) {
        int row = susp[2 + i];
        int bb = row >> 12;
        __syncthreads();
        {
            const float* xr = x + (size_t)row * DIM;
            const float* wr = Wtq + (size_t)tid * DIM;
            float a = 0.f;
            for (int d = 0; d < DIM; d += 4) {
                float4 xv = *(const float4*)(xr + d);
                float4 wv = *(const float4*)(wr + d);
                a = fmaf(xv.x, wv.x, a); a = fmaf(xv.y, wv.y, a);
                a = fmaf(xv.z, wv.z, a); a = fmaf(xv.w, wv.w, a);
            }
            qrow[tid] = a;
        }
        __syncthreads();

        int c = tid & 7, g = tid >> 3;
        float m = -INFINITY, l = 0.f; int am = 0;
        for (int n0 = 0; n0 < NSEQ; n0 += 32) {
            int n = n0 + g;
            const float* kr = kf + ((size_t)bb * NSEQ + n) * DIM;
            float dot = 0.f;
#pragma unroll
            for (int j = 0; j < 8; ++j) {
                int d = (j * 8 + c) * 4;
                float4 kv = *(const float4*)(kr + d);
                dot = fmaf(qrow[d], kv.x, dot);     dot = fmaf(qrow[d + 1], kv.y, dot);
                dot = fmaf(qrow[d + 2], kv.z, dot); dot = fmaf(qrow[d + 3], kv.w, dot);
            }
#pragma unroll
            for (int dd = 1; dd < 8; dd <<= 1) dot += __shfl_xor(dot, dd);
            float s = dot * SCALE;
            if (s > m) { l = l * __expf(m - s) + 1.f; m = s; am = bb * NSEQ + n; }
            else       { l += __expf(s - m); }
        }
#pragma unroll
        for (int dd = 8; dd < 64; dd <<= 1) {
            float m2 = __shfl_xor(m, dd); float l2 = __shfl_xor(l, dd); int a2 = __shfl_xor(am, dd);
            if (m2 > m) { l = l * __expf(m - m2) + l2; m = m2; am = a2; }
            else        { l += l2 * __expf(m2 - m); }
        }
        if ((tid & 63) == 0) { rmw[tid >> 6] = m; rlw[tid >> 6] = l; raw_[tid >> 6] = am; }
        __syncthreads();
        if (tid == 0) {
            float M = rmw[0], L = rlw[0]; int A = raw_[0];
            for (int wv = 1; wv < 4; ++wv) {
                float m2 = rmw[wv], l2 = rlw[wv]; int a2 = raw_[wv];
                if (m2 > M) { L = L * __expf(M - m2) + l2; M = m2; A = a2; }
                else        { L += l2 * __expf(m2 - M); }
            }
            float p = 1.f / L;
            scl[row] = (p >= THRESH) ? p : 0.f;
            sidx[row] = A;
        }
    }
}

// ---------------------------------------------------------------------------
// Stage 3: out[r] = scl[r] * (vh[idx[r]] @ Wp) + bp  (fp16 MFMA, fp32 scale)
// ---------------------------------------------------------------------------
__global__ __launch_bounds__(256, 2)
void out_mfma(const _Float16* __restrict__ vh, const _Float16* __restrict__ Wph,
              const float* __restrict__ scl, const int* __restrict__ sidx,
              const float* __restrict__ bp, float* __restrict__ out)
{
    __shared__ half8 sA[1024];
    __shared__ half8 sB[1024];
    int tid = threadIdx.x, w = tid >> 6, ln = tid & 63;
    int rb = blockIdx.x * 128, cb = blockIdx.y * 128;

    f32x4 acc[2][8];
#pragma unroll
    for (int mi = 0; mi < 2; ++mi)
#pragma unroll
        for (int nt = 0; nt < 8; ++nt) acc[mi][nt] = (f32x4){0.f, 0.f, 0.f, 0.f};

    int r = tid >> 1, chalf = (tid & 1) * 4;
    int gix = sidx[rb + r];
    for (int kc = 0; kc < 4; ++kc) {
        __syncthreads();
        const _Float16* asrc = vh + (size_t)gix * DIM + kc * 64 + chalf * 8;
        const _Float16* bsrc = Wph + (size_t)(cb + r) * DIM + kc * 64 + chalf * 8;
#pragma unroll
        for (int cc = 0; cc < 4; ++cc) {
            int c = chalf + cc;
            int li = ((r >> 4) * 2 + (c >> 2)) * 64 + ((c & 3) << 4) + (r & 15);
            sA[li] = *(const half8*)(asrc + cc * 8);
            sB[li] = *(const half8*)(bsrc + cc * 8);
        }
        __syncthreads();
#pragma unroll
        for (int s = 0; s < 2; ++s) {
            half8 a0 = sA[((w * 2 + 0) * 2 + s) * 64 + ln];
            half8 a1 = sA[((w * 2 + 1) * 2 + s) * 64 + ln];
#pragma unroll
            for (int nt = 0; nt < 8; ++nt) {
                half8 bv = sB[(nt * 2 + s) * 64 + ln];
                acc[0][nt] = __builtin_amdgcn_mfma_f32_16x16x32_f16(a0, bv, acc[0][nt], 0, 0, 0);
                acc[1][nt] = __builtin_amdgcn_mfma_f32_16x16x32_f16(a1, bv, acc[1][nt], 0, 0, 0);
            }
        }
    }
    int quad = ln >> 4, cix = ln & 15;
#pragma unroll
    for (int mi = 0; mi < 2; ++mi)
#pragma unroll
        for (int rr = 0; rr < 4; ++rr) {
            int row = rb + (w * 2 + mi) * 16 + quad * 4 + rr;
            float sc = scl[row];
#pragma unroll
            for (int nt = 0; nt < 8; ++nt) {
                int col = cb + nt * 16 + cix;
                out[(size_t)row * DIM + col] = acc[mi][nt][rr] * sc + bp[col];
            }
        }
}

// ---------------------------------------------------------------------------
extern "C" void kernel_launch(void* const* d_in, const int* in_sizes, int n_in,
                              void* d_out, int out_size, void* d_ws, size_t ws_size,
                              hipStream_t stream)
{
    (void)in_sizes; (void)n_in; (void)out_size; (void)ws_size;
    const float* x  = (const float*)d_in[0];
    const float* y  = (const float*)d_in[1];
    const float* Wq = (const float*)d_in[2];
    const float* Wk = (const float*)d_in[3];
    const float* Wv = (const float*)d_in[4];
    const float* Wp = (const float*)d_in[5];
    const float* bp = (const float*)d_in[6];
    float* out = (float*)d_out;

    // ws layout (~44 MB)
    float* p0 = (float*)d_ws;
    float* kf = p0;                 p0 += 4194304;
    float* Wt = p0;                 p0 += 65536;          // fp32 Wq^T only (recheck)
    _Float16* Wth = (_Float16*)p0;  p0 += 4 * 65536 / 2;
    _Float16* qh  = (_Float16*)p0;  p0 += 2097152;
    _Float16* kh  = (_Float16*)p0;  p0 += 2097152;
    _Float16* vh  = (_Float16*)p0;  p0 += 2097152;
    float* pm  = p0;                p0 += 65536;
    float* pl  = p0;                p0 += 65536;
    int*  pam  = (int*)p0;          p0 += 65536;
    float* scl = p0;                p0 += 16384;
    int*  sidx = (int*)p0;          p0 += 16384;
    int*  susp = (int*)p0;

    prep_kernel<<<64, 256, 0, stream>>>(Wq, Wk, Wv, Wp, Wt, Wth, susp);
    proj3_mfma<<<dim3(128, 2, 3), 256, 0, stream>>>(x, y, Wth, qh, kh, kf, vh);
    flash_fp16<<<dim3(16, 32), 256, 0, stream>>>(qh, kh, pm, pl, pam);
    merge_kernel<<<64, 256, 0, stream>>>(pm, pl, pam, scl, sidx, susp);
    recheck_kernel<<<256, 256, 0, stream>>>(x, Wt, kf, susp, scl, sidx);
    out_mfma<<<dim3(128, 2), 256, 0, stream>>>(vh, Wth + 3 * 65536, scl, sidx, bp, out);
}

// Round 6
// 226.671 us; speedup vs baseline: 3.0323x; 1.1440x over previous
//
#include <hip/hip_runtime.h>
#include <cstdint>
#include <cmath>

#define DIM     256
#define NSEQ    4096
#define SCALE   0.17677669529663687f   // 32^-0.5
#define THRESH  0.6f
#define BAND    0.01f                  // recheck guard band
#define MAXSUSP 8000
#define NCHUNK  32                     // 4096 keys / 128

using half8 = __attribute__((ext_vector_type(8))) _Float16;
using half4 = __attribute__((ext_vector_type(4))) _Float16;
using f32x4 = __attribute__((ext_vector_type(4))) float;

// ---------------------------------------------------------------------------
// Prep: coalesced LDS-tiled transpose. Wth[m][c][k] = W_m[k][c] (fp16);
// Wt[c][k] = Wq[k][c] (fp32, recheck only). Zeroes susp.
// ---------------------------------------------------------------------------
__global__ void prep_kernel(const float* __restrict__ W0, const float* __restrict__ W1,
                            const float* __restrict__ W2, const float* __restrict__ W3,
                            float* __restrict__ Wt, _Float16* __restrict__ Wth,
                            int* __restrict__ susp)
{
    __shared__ float tile[64][68];
    int t = threadIdx.x;
    int m = blockIdx.x >> 4;
    int ti = blockIdx.x & 15;
    int tr = (ti >> 2) * 64, tc = (ti & 3) * 64;
    const float* W = (m == 0) ? W0 : (m == 1) ? W1 : (m == 2) ? W2 : W3;
    if (blockIdx.x == 0 && t < 2) susp[t] = 0;
    int rr = t >> 4, c4 = (t & 15) * 4;
#pragma unroll
    for (int p = 0; p < 4; ++p) {
        int row = p * 16 + rr;
        *(float4*)&tile[row][c4] = *(const float4*)(W + (size_t)(tr + row) * DIM + tc + c4);
    }
    __syncthreads();
#pragma unroll
    for (int p = 0; p < 4; ++p) {
        int c = p * 16 + rr;
        float4 v;
        v.x = tile[c4 + 0][c]; v.y = tile[c4 + 1][c];
        v.z = tile[c4 + 2][c]; v.w = tile[c4 + 3][c];
        size_t ot = (size_t)(tc + c) * DIM + tr + c4;
        if (m == 0) *(float4*)(Wt + ot) = v;
        half4 hv;
        hv[0] = (_Float16)v.x; hv[1] = (_Float16)v.y;
        hv[2] = (_Float16)v.z; hv[3] = (_Float16)v.w;
        *(half4*)(Wth + (size_t)m * 65536 + ot) = hv;
    }
}

// ---------------------------------------------------------------------------
// Stage 1: q=x@Wq, k=y@Wk, v=x@Wv via fp16 MFMA (fp32 acc).
// ---------------------------------------------------------------------------
__global__ __launch_bounds__(256, 2)
void proj3_mfma(const float* __restrict__ x, const float* __restrict__ y,
                const _Float16* __restrict__ Wth,
                _Float16* __restrict__ qh, _Float16* __restrict__ kh,
                float* __restrict__ kf, _Float16* __restrict__ vh)
{
    __shared__ half8 sA[1024];
    __shared__ half8 sB[1024];
    int tid = threadIdx.x, w = tid >> 6, ln = tid & 63;
    int rb = blockIdx.x * 128, cb = blockIdx.y * 128, m = blockIdx.z;
    const float* A = (m == 1) ? y : x;
    const _Float16* B = Wth + (size_t)m * 65536;

    f32x4 acc[2][8];
#pragma unroll
    for (int mi = 0; mi < 2; ++mi)
#pragma unroll
        for (int nt = 0; nt < 8; ++nt) acc[mi][nt] = (f32x4){0.f, 0.f, 0.f, 0.f};

    int r = tid >> 1;
    int chalf = (tid & 1) * 4;
    for (int kc = 0; kc < 4; ++kc) {
        __syncthreads();
        const float*    asrc = A + (size_t)(rb + r) * DIM + kc * 64 + chalf * 8;
        const _Float16* bsrc = B + (size_t)(cb + r) * DIM + kc * 64 + chalf * 8;
#pragma unroll
        for (int cc = 0; cc < 4; ++cc) {
            int c = chalf + cc;
            float4 f0 = *(const float4*)(asrc + cc * 8);
            float4 f1 = *(const float4*)(asrc + cc * 8 + 4);
            half8 hv;
            hv[0] = (_Float16)f0.x; hv[1] = (_Float16)f0.y; hv[2] = (_Float16)f0.z; hv[3] = (_Float16)f0.w;
            hv[4] = (_Float16)f1.x; hv[5] = (_Float16)f1.y; hv[6] = (_Float16)f1.z; hv[7] = (_Float16)f1.w;
            int li = ((r >> 4) * 2 + (c >> 2)) * 64 + ((c & 3) << 4) + (r & 15);
            sA[li] = hv;
            sB[li] = *(const half8*)(bsrc + cc * 8);
        }
        __syncthreads();
#pragma unroll
        for (int s = 0; s < 2; ++s) {
            half8 a0 = sA[((w * 2 + 0) * 2 + s) * 64 + ln];
            half8 a1 = sA[((w * 2 + 1) * 2 + s) * 64 + ln];
#pragma unroll
            for (int nt = 0; nt < 8; ++nt) {
                half8 bv = sB[(nt * 2 + s) * 64 + ln];
                acc[0][nt] = __builtin_amdgcn_mfma_f32_16x16x32_f16(a0, bv, acc[0][nt], 0, 0, 0);
                acc[1][nt] = __builtin_amdgcn_mfma_f32_16x16x32_f16(a1, bv, acc[1][nt], 0, 0, 0);
            }
        }
    }
    int quad = ln >> 4, cix = ln & 15;
#pragma unroll
    for (int mi = 0; mi < 2; ++mi)
#pragma unroll
        for (int nt = 0; nt < 8; ++nt)
#pragma unroll
            for (int rr = 0; rr < 4; ++rr) {
                int row = rb + (w * 2 + mi) * 16 + quad * 4 + rr;
                int col = cb + nt * 16 + cix;
                size_t off = (size_t)row * DIM + col;
                float vv = acc[mi][nt][rr];
                if (m == 0)      qh[off] = (_Float16)vv;
                else if (m == 1) { kh[off] = (_Float16)vv; kf[off] = vv; }
                else             vh[off] = (_Float16)vv;
            }
}

// ---------------------------------------------------------------------------
// Stage 2: fp16 MFMA flash score pass (q frags in registers, k L2-resident).
// ---------------------------------------------------------------------------
__global__ __launch_bounds__(256, 2)
void flash_fp16(const _Float16* __restrict__ qh, const _Float16* __restrict__ kh,
                float* __restrict__ pm, float* __restrict__ pl, int* __restrict__ pam)
{
    __shared__ half8 sK[4096];   // 128 keys x 256 dims fp16 = 64 KB
    int tid = threadIdx.x, w = tid >> 6, ln = tid & 63;
    int g = blockIdx.x;          // ms + 4*b
    int qt = blockIdx.y;
    int ms = g & 3, b = g >> 2;
    size_t qbase = (size_t)b * NSEQ + qt * 128 + w * 32;
    size_t krow0 = (size_t)b * NSEQ + ms * 1024;

    half8 qf[2][8];
#pragma unroll
    for (int mi = 0; mi < 2; ++mi) {
        const _Float16* qsrc = qh + (qbase + mi * 16 + (ln & 15)) * DIM + (ln >> 4) * 8;
#pragma unroll
        for (int ks = 0; ks < 8; ++ks)
            qf[mi][ks] = *(const half8*)(qsrc + ks * 32);
    }

    float rm[2][4], rl[2][4]; int ram[2][4];
#pragma unroll
    for (int mi = 0; mi < 2; ++mi)
#pragma unroll
        for (int rr = 0; rr < 4; ++rr) { rm[mi][rr] = -INFINITY; rl[mi][rr] = 0.f; ram[mi][rr] = 0; }

    int r = tid >> 1, h = tid & 1;
    int nt_ = r >> 4, m_ = r & 15;
    for (int kt = 0; kt < 8; ++kt) {
        __syncthreads();
        const _Float16* ksrc = kh + (krow0 + kt * 128 + r) * DIM + h * 128;
#pragma unroll
        for (int cc = 0; cc < 16; ++cc) {
            int c = h * 16 + cc;
            sK[(nt_ * 8 + (c >> 2)) * 64 + ((c & 3) << 4) + m_] = *(const half8*)(ksrc + cc * 8);
        }
        __syncthreads();

        f32x4 acc[2][8];
#pragma unroll
        for (int mi = 0; mi < 2; ++mi)
#pragma unroll
            for (int nt = 0; nt < 8; ++nt) acc[mi][nt] = (f32x4){0.f, 0.f, 0.f, 0.f};

#pragma unroll
        for (int nt = 0; nt < 8; ++nt)
#pragma unroll
            for (int ks = 0; ks < 8; ++ks) {
                half8 bk = sK[(nt * 8 + ks) * 64 + ln];
                acc[0][nt] = __builtin_amdgcn_mfma_f32_16x16x32_f16(qf[0][ks], bk, acc[0][nt], 0, 0, 0);
                acc[1][nt] = __builtin_amdgcn_mfma_f32_16x16x32_f16(qf[1][ks], bk, acc[1][nt], 0, 0, 0);
            }

        int keybase = b * NSEQ + ms * 1024 + kt * 128 + (ln & 15);
#pragma unroll
        for (int mi = 0; mi < 2; ++mi)
#pragma unroll
            for (int rr = 0; rr < 4; ++rr) {
                float mx = rm[mi][rr]; int amx = ram[mi][rr];
                float sv[8];
#pragma unroll
                for (int nt = 0; nt < 8; ++nt) {
                    sv[nt] = acc[mi][nt][rr] * SCALE;
                    if (sv[nt] > mx) { mx = sv[nt]; amx = keybase + nt * 16; }
                }
                float sum = 0.f;
#pragma unroll
                for (int nt = 0; nt < 8; ++nt) sum += __expf(sv[nt] - mx);
                rl[mi][rr] = rl[mi][rr] * __expf(rm[mi][rr] - mx) + sum;
                rm[mi][rr] = mx; ram[mi][rr] = amx;
            }
    }

#pragma unroll
    for (int mi = 0; mi < 2; ++mi)
#pragma unroll
        for (int rr = 0; rr < 4; ++rr) {
            float m0 = rm[mi][rr], l0 = rl[mi][rr]; int am0 = ram[mi][rr];
#pragma unroll
            for (int d = 1; d < 16; d <<= 1) {
                float m2 = __shfl_xor(m0, d);
                float l2 = __shfl_xor(l0, d);
                int  am2 = __shfl_xor(am0, d);
                if (m2 > m0) { l0 = l0 * __expf(m0 - m2) + l2; m0 = m2; am0 = am2; }
                else         { l0 = l0 + l2 * __expf(m2 - m0); }
            }
            if ((ln & 15) == 0) {
                int row = b * NSEQ + qt * 128 + w * 32 + mi * 16 + (ln >> 4) * 4 + rr;
                pm[row * 4 + ms] = m0; pl[row * 4 + ms] = l0; pam[row * 4 + ms] = am0;
            }
        }
}

// ---------------------------------------------------------------------------
// Stage 2b: merge 4 ms-split partials -> (scale, idx); flag near-boundary rows.
// ---------------------------------------------------------------------------
__global__ void merge_kernel(const float* __restrict__ pm, const float* __restrict__ pl,
                             const int* __restrict__ pam,
                             float* __restrict__ scl, int* __restrict__ sidx,
                             int* __restrict__ susp)
{
    int row = blockIdx.x * 256 + threadIdx.x;
    float m = -INFINITY, l = 0.f; int am = 0;
#pragma unroll
    for (int s = 0; s < 4; ++s) {
        float m2 = pm[row * 4 + s];
        float l2 = pl[row * 4 + s];
        int  am2 = pam[row * 4 + s];
        if (m2 > m) { l = l * __expf(m - m2) + l2; m = m2; am = am2; }
        else        { l = l + l2 * __expf(m2 - m); }
    }
    float p = 1.f / l;
    scl[row] = (p >= THRESH) ? p : 0.f;
    sidx[row] = am;
    if (fabsf(p - THRESH) < BAND) {
        int i = atomicAdd(susp, 1);
        if (i < MAXSUSP) susp[2 + i] = row;
    }
}

// ---------------------------------------------------------------------------
// Stage 2c-1: fp32 q-rows for suspects (Wq^T is L2-resident).
// ---------------------------------------------------------------------------
__global__ __launch_bounds__(256)
void recheck_q(const float* __restrict__ x, const float* __restrict__ Wtq,
               const int* __restrict__ susp, float* __restrict__ qsusp)
{
    int tid = threadIdx.x;
    int count = susp[0]; if (count > MAXSUSP) count = MAXSUSP;
    for (int i = blockIdx.x; i < count; i += gridDim.x) {
        int row = susp[2 + i];
        const float* xr = x + (size_t)row * DIM;
        const float* wr = Wtq + (size_t)tid * DIM;
        float a = 0.f;
        for (int d = 0; d < DIM; d += 4) {
            float4 xv = *(const float4*)(xr + d);
            float4 wv = *(const float4*)(wr + d);
            a = fmaf(xv.x, wv.x, a); a = fmaf(xv.y, wv.y, a);
            a = fmaf(xv.z, wv.z, a); a = fmaf(xv.w, wv.w, a);
        }
        qsusp[(size_t)i * DIM + tid] = a;
    }
}

// ---------------------------------------------------------------------------
// Stage 2c-2: key-parallel exact partials. Block = (chunk of 128 keys, suspect).
// 2 threads per key; per-wave butterfly; cross-wave LDS fold -> one partial.
// ---------------------------------------------------------------------------
__global__ __launch_bounds__(256)
void recheck_part(const float* __restrict__ qsusp, const float* __restrict__ kf,
                  const int* __restrict__ susp,
                  float* __restrict__ pmP, float* __restrict__ plP, int* __restrict__ pamP)
{
    __shared__ float qs[DIM];
    __shared__ float wm[4], wl[4]; __shared__ int wa[4];
    int tid = threadIdx.x;
    int chunk = blockIdx.x;                 // 0..31
    int count = susp[0]; if (count > MAXSUSP) count = MAXSUSP;

    for (int i = blockIdx.y; i < count; i += gridDim.y) {
        int row = susp[2 + i];
        int bb = row >> 12;
        __syncthreads();                    // protect qs/wm from prior iter
        qs[tid] = qsusp[(size_t)i * DIM + tid];
        __syncthreads();

        int key = tid >> 1, h = tid & 1;
        int gkey = bb * NSEQ + chunk * 128 + key;
        const float* kr = kf + (size_t)gkey * DIM + h * 128;
        const float* qp = qs + h * 128;
        float dot = 0.f;
#pragma unroll
        for (int j = 0; j < 32; ++j) {
            float4 kv = *(const float4*)(kr + j * 4);
            float4 qv = *(const float4*)(qp + j * 4);
            dot = fmaf(qv.x, kv.x, dot); dot = fmaf(qv.y, kv.y, dot);
            dot = fmaf(qv.z, kv.z, dot); dot = fmaf(qv.w, kv.w, dot);
        }
        dot += __shfl_xor(dot, 1);          // combine the two halves
        float s = dot * SCALE;

        // per-lane state: only even lanes contribute (odd lanes neutral)
        float m = (h == 0) ? s : -INFINITY;
        float l = (h == 0) ? 1.f : 0.f;
        int  am = (h == 0) ? gkey : 0;
#pragma unroll
        for (int d = 1; d < 64; d <<= 1) {
            float m2 = __shfl_xor(m, d);
            float l2 = __shfl_xor(l, d);
            int  a2 = __shfl_xor(am, d);
            if (m2 > m) { l = l * __expf(m - m2) + l2; m = m2; am = a2; }
            else        { l = l + l2 * __expf(m2 - m); }
        }
        if ((tid & 63) == 0) { wm[tid >> 6] = m; wl[tid >> 6] = l; wa[tid >> 6] = am; }
        __syncthreads();
        if (tid == 0) {
            float M = wm[0], L = wl[0]; int A = wa[0];
#pragma unroll
            for (int wv = 1; wv < 4; ++wv) {
                float m2 = wm[wv], l2 = wl[wv]; int a2 = wa[wv];
                if (m2 > M) { L = L * __expf(M - m2) + l2; M = m2; A = a2; }
                else        { L += l2 * __expf(m2 - M); }
            }
            size_t o = (size_t)i * NCHUNK + chunk;
            pmP[o] = M; plP[o] = L; pamP[o] = A;
        }
    }
}

// ---------------------------------------------------------------------------
// Stage 2c-3: fold 32 chunk-partials per suspect -> final (scale, idx).
// ---------------------------------------------------------------------------
__global__ __launch_bounds__(256)
void recheck_fold(const float* __restrict__ pmP, const float* __restrict__ plP,
                  const int* __restrict__ pamP, const int* __restrict__ susp,
                  float* __restrict__ scl, int* __restrict__ sidx)
{
    int count = susp[0]; if (count > MAXSUSP) count = MAXSUSP;
    for (int i = blockIdx.x * 256 + threadIdx.x; i < count; i += gridDim.x * 256) {
        float M = -INFINITY, L = 0.f; int A = 0;
#pragma unroll
        for (int c = 0; c < NCHUNK; ++c) {
            size_t o = (size_t)i * NCHUNK + c;
            float m2 = pmP[o], l2 = plP[o]; int a2 = pamP[o];
            if (m2 > M) { L = L * __expf(M - m2) + l2; M = m2; A = a2; }
            else        { L += l2 * __expf(m2 - M); }
        }
        float p = 1.f / L;
        int row = susp[2 + i];
        scl[row] = (p >= THRESH) ? p : 0.f;
        sidx[row] = A;
    }
}

// ---------------------------------------------------------------------------
// Stage 3: out[r] = scl[r] * (vh[idx[r]] @ Wp) + bp
// ---------------------------------------------------------------------------
__global__ __launch_bounds__(256, 2)
void out_mfma(const _Float16* __restrict__ vh, const _Float16* __restrict__ Wph,
              const float* __restrict__ scl, const int* __restrict__ sidx,
              const float* __restrict__ bp, float* __restrict__ out)
{
    __shared__ half8 sA[1024];
    __shared__ half8 sB[1024];
    int tid = threadIdx.x, w = tid >> 6, ln = tid & 63;
    int rb = blockIdx.x * 128, cb = blockIdx.y * 128;

    f32x4 acc[2][8];
#pragma unroll
    for (int mi = 0; mi < 2; ++mi)
#pragma unroll
        for (int nt = 0; nt < 8; ++nt) acc[mi][nt] = (f32x4){0.f, 0.f, 0.f, 0.f};

    int r = tid >> 1, chalf = (tid & 1) * 4;
    int gix = sidx[rb + r];
    for (int kc = 0; kc < 4; ++kc) {
        __syncthreads();
        const _Float16* asrc = vh + (size_t)gix * DIM + kc * 64 + chalf * 8;
        const _Float16* bsrc = Wph + (size_t)(cb + r) * DIM + kc * 64 + chalf * 8;
#pragma unroll
        for (int cc = 0; cc < 4; ++cc) {
            int c = chalf + cc;
            int li = ((r >> 4) * 2 + (c >> 2)) * 64 + ((c & 3) << 4) + (r & 15);
            sA[li] = *(const half8*)(asrc + cc * 8);
            sB[li] = *(const half8*)(bsrc + cc * 8);
        }
        __syncthreads();
#pragma unroll
        for (int s = 0; s < 2; ++s) {
            half8 a0 = sA[((w * 2 + 0) * 2 + s) * 64 + ln];
            half8 a1 = sA[((w * 2 + 1) * 2 + s) * 64 + ln];
#pragma unroll
            for (int nt = 0; nt < 8; ++nt) {
                half8 bv = sB[(nt * 2 + s) * 64 + ln];
                acc[0][nt] = __builtin_amdgcn_mfma_f32_16x16x32_f16(a0, bv, acc[0][nt], 0, 0, 0);
                acc[1][nt] = __builtin_amdgcn_mfma_f32_16x16x32_f16(a1, bv, acc[1][nt], 0, 0, 0);
            }
        }
    }
    int quad = ln >> 4, cix = ln & 15;
#pragma unroll
    for (int mi = 0; mi < 2; ++mi)
#pragma unroll
        for (int rr = 0; rr < 4; ++rr) {
            int row = rb + (w * 2 + mi) * 16 + quad * 4 + rr;
            float sc = scl[row];
#pragma unroll
            for (int nt = 0; nt < 8; ++nt) {
                int col = cb + nt * 16 + cix;
                out[(size_t)row * DIM + col] = acc[mi][nt][rr] * sc + bp[col];
            }
        }
}

// ---------------------------------------------------------------------------
extern "C" void kernel_launch(void* const* d_in, const int* in_sizes, int n_in,
                              void* d_out, int out_size, void* d_ws, size_t ws_size,
                              hipStream_t stream)
{
    (void)in_sizes; (void)n_in; (void)out_size; (void)ws_size;
    const float* x  = (const float*)d_in[0];
    const float* y  = (const float*)d_in[1];
    const float* Wq = (const float*)d_in[2];
    const float* Wk = (const float*)d_in[3];
    const float* Wv = (const float*)d_in[4];
    const float* Wp = (const float*)d_in[5];
    const float* bp = (const float*)d_in[6];
    float* out = (float*)d_out;

    // ws layout (~56 MB)
    float* p0 = (float*)d_ws;
    float* kf = p0;                 p0 += 4194304;
    float* Wt = p0;                 p0 += 65536;          // fp32 Wq^T (recheck)
    _Float16* Wth = (_Float16*)p0;  p0 += 4 * 65536 / 2;
    _Float16* qh  = (_Float16*)p0;  p0 += 2097152;
    _Float16* kh  = (_Float16*)p0;  p0 += 2097152;
    _Float16* vh  = (_Float16*)p0;  p0 += 2097152;
    float* pm  = p0;                p0 += 65536;
    float* pl  = p0;                p0 += 65536;
    int*  pam  = (int*)p0;          p0 += 65536;
    float* scl = p0;                p0 += 16384;
    int*  sidx = (int*)p0;          p0 += 16384;
    int*  susp = (int*)p0;          p0 += MAXSUSP + 2 + 2;
    float* qsusp = p0;              p0 += (size_t)MAXSUSP * DIM;
    float* pmP = p0;                p0 += (size_t)MAXSUSP * NCHUNK;
    float* plP = p0;                p0 += (size_t)MAXSUSP * NCHUNK;
    int*  pamP = (int*)p0;

    prep_kernel<<<64, 256, 0, stream>>>(Wq, Wk, Wv, Wp, Wt, Wth, susp);
    proj3_mfma<<<dim3(128, 2, 3), 256, 0, stream>>>(x, y, Wth, qh, kh, kf, vh);
    flash_fp16<<<dim3(16, 32), 256, 0, stream>>>(qh, kh, pm, pl, pam);
    merge_kernel<<<64, 256, 0, stream>>>(pm, pl, pam, scl, sidx, susp);
    recheck_q<<<128, 256, 0, stream>>>(x, Wt, susp, qsusp);
    recheck_part<<<dim3(NCHUNK, 64), 256, 0, stream>>>(qsusp, kf, susp, pmP, plP, pamP);
    recheck_fold<<<8, 256, 0, stream>>>(pmP, plP, pamP, susp, scl, sidx);
    out_mfma<<<dim3(128, 2), 256, 0, stream>>>(vh, Wth + 3 * 65536, scl, sidx, bp, out);
}